// Round 8
// baseline (50.352 us; speedup 1.0000x reference)
//
#include <hip/hip_runtime.h>
#include <cstdint>

#define T_STEPS 16
#define V_VECS  1024
#define D_DIM   128
#define B_BATCH 2048
#define BCAP    2048          // per-t list capacity (bulletproof: n <= B)

// ---------------------------------------------------------------------------
// k_score: grid (16 vtiles, 16 t, 2 z), block = 64 threads (ONE wave).
// 8x8 register tile per thread => 64v x 64b block tile, 1 B/FMA LDS traffic
// (vs 2 B/FMA for the old 4x4/256t version) -> VALU-bound ~6.8us instead of
// LDS-bound ~10.3us.
//
// Phase 0: barrier-free wave-ballot bucketing (32 rounds). Deterministic =>
//          all blocks of t derive the IDENTICAL blist.
// Phase 1: stage A^T k-major (row v = lane, 32 float4 each), fused per-row
//          inverse norm (lane owns row v=lane, no reduce needed).
// Phase 2: chunk loop (cs = z*64; cs += 128): stage X^T k-major, then per k:
//          4x ds_read_b128 (2-way bank alias = free) + 64 FMA into acc[8][8].
//          Epilogue: invnorm scale, argmax over 8 local v, shfl_xor {1,2,4}
//          across iv lanes (tie -> lowest v, matches jnp.argmax), plain store
//          of packed (ordered_score:32 | (1023-v):16 | b:16) to
//          partial[vt][t][bi]. Cross-block visibility via the KERNEL
//          BOUNDARY only (intra-kernel protocols failed rounds 4-6).
// ---------------------------------------------------------------------------
__global__ __launch_bounds__(64) void k_score(const float* __restrict__ X,
                                              const float* __restrict__ L,
                                              const int* __restrict__ idx,
                                              unsigned long long* __restrict__ partial,
                                              int* __restrict__ counts) {
    __shared__ __align__(16) float As[D_DIM][64];   // 32 KB
    __shared__ __align__(16) float Xs[D_DIM][64];   // 32 KB
    __shared__ float invn_s[64];
    __shared__ int   blist[BCAP];                   // 8 KB

    const int t    = blockIdx.y;
    const int vt   = blockIdx.x;
    const int v0   = vt * 64;
    const int z    = blockIdx.z;
    const int lane = threadIdx.x;                   // 0..63

    // ---- phase 0: wave-ballot bucketing (no barriers, wave-synchronous) ----
    int n = 0;
    for (int r = 0; r < 32; ++r) {
        const int b = r * 64 + lane;
        const bool m = (idx[b] == t);
        const unsigned long long bal = __ballot(m);
        if (m) blist[n + __popcll(bal & ((1ull << lane) - 1ull))] = b;
        n += __popcll(bal);
    }
    if (vt == 0 && z == 0 && lane == 0) counts[t] = n;   // before early return
    if (z * 64 >= n) return;             // uniform across blocks of t

    // ---- phase 1: stage A^T (k-major) + fused per-row inverse norm ----
    const float4* LA = (const float4*)(L + (size_t)(t * V_VECS + v0) * D_DIM);
    float ss = 0.f;
    #pragma unroll 8
    for (int p = 0; p < 32; ++p) {
        const float4 g = LA[lane * 32 + p];
        As[4 * p + 0][lane] = g.x;
        As[4 * p + 1][lane] = g.y;
        As[4 * p + 2][lane] = g.z;
        As[4 * p + 3][lane] = g.w;
        ss += g.x * g.x + g.y * g.y + g.z * g.z + g.w * g.w;
    }
    invn_s[lane] = rsqrtf(fmaxf(ss, 1e-12f));

    const int iv = lane & 7;             // v-octet: v = v0 + iv*8 + i
    const int jb = lane >> 3;            // b-octet: b-slot = cs + jb*8 + j
    const float4* XA = (const float4*)X;

    // ---- phase 2: chunk loop ----
    for (int cs = z * 64; cs < n; cs += 128) {
        __syncthreads();                 // prior Xs reads done; blist/As settled

        const int bl = cs + lane;
        const int bg = (bl < n) ? blist[bl] : -1;
        const float4* xr = XA + (size_t)(bg < 0 ? 0 : bg) * 32;
        #pragma unroll 8
        for (int p = 0; p < 32; ++p) {
            float4 g = make_float4(0.f, 0.f, 0.f, 0.f);
            if (bg >= 0) g = xr[p];
            Xs[4 * p + 0][lane] = g.x;
            Xs[4 * p + 1][lane] = g.y;
            Xs[4 * p + 2][lane] = g.z;
            Xs[4 * p + 3][lane] = g.w;
        }
        __syncthreads();

        float acc[8][8] = {};
        #pragma unroll 4
        for (int k = 0; k < D_DIM; ++k) {
            const float4 a0 = *(const float4*)&As[k][iv * 8];
            const float4 a1 = *(const float4*)&As[k][iv * 8 + 4];
            const float4 x0 = *(const float4*)&Xs[k][jb * 8];
            const float4 x1 = *(const float4*)&Xs[k][jb * 8 + 4];
            const float a[8] = {a0.x, a0.y, a0.z, a0.w, a1.x, a1.y, a1.z, a1.w};
            const float x[8] = {x0.x, x0.y, x0.z, x0.w, x1.x, x1.y, x1.z, x1.w};
            #pragma unroll
            for (int i = 0; i < 8; ++i)
                #pragma unroll
                for (int j = 0; j < 8; ++j)
                    acc[i][j] += a[i] * x[j];
        }

        // ---- epilogue: argmax over v per b ----
        const float4 n0 = *(const float4*)&invn_s[iv * 8];
        const float4 n1 = *(const float4*)&invn_s[iv * 8 + 4];
        const float inv[8] = {n0.x, n0.y, n0.z, n0.w, n1.x, n1.y, n1.z, n1.w};

        #pragma unroll
        for (int j = 0; j < 8; ++j) {
            float s = acc[0][j] * inv[0];
            int   c = v0 + iv * 8;
            #pragma unroll
            for (int i = 1; i < 8; ++i) {
                const float si = acc[i][j] * inv[i];
                const int   ci = v0 + iv * 8 + i;
                if (si > s) { s = si; c = ci; }      // strict: lowest v wins tie
            }
            #pragma unroll
            for (int m = 1; m <= 4; m <<= 1) {       // reduce across iv lanes
                const float u  = __shfl_xor(s, m);
                const int   cu = __shfl_xor(c, m);
                if (u > s || (u == s && cu < c)) { s = u; c = cu; }
            }
            if (iv == 0) {
                const int bi = cs + jb * 8 + j;
                if (bi < n) {
                    unsigned int ub = __float_as_uint(s);
                    ub = (ub & 0x80000000u) ? ~ub : (ub | 0x80000000u);
                    const unsigned long long key =
                        ((unsigned long long)ub << 32) |
                        ((unsigned long long)(unsigned)(1023 - c) << 16) |
                        (unsigned long long)(unsigned)blist[bi];
                    partial[((size_t)vt * T_STEPS + t) * BCAP + bi] = key;
                }
            }
        }
    }
}

// ---------------------------------------------------------------------------
// k_gather: grid (32 bi-chunks, 16 t), block 256. Reads counts/partial across
// the kernel boundary (full visibility). Per valid bi: max-reduce the 16
// vt-keys (higher score wins; tie -> higher (1023-v) -> lower v, matching
// jnp.argmax), decode (b, v), copy the raw winning vector (bit-exact).
// ---------------------------------------------------------------------------
__global__ __launch_bounds__(256) void k_gather(const float* __restrict__ L,
                                                const int* __restrict__ counts,
                                                const unsigned long long* __restrict__ partial,
                                                float* __restrict__ out) {
    __shared__ int vArr[64];
    __shared__ int bArr[64];

    const int t  = blockIdx.y;
    const int cs = blockIdx.x * 64;
    const int n  = counts[t];
    if (cs >= n) return;

    const int tid = threadIdx.x;
    const int nb  = min(64, n - cs);
    if (tid < nb) {
        const int bi = cs + tid;
        unsigned long long best = partial[(size_t)t * BCAP + bi];   // vt=0
        #pragma unroll
        for (int q = 1; q < 16; ++q) {
            const unsigned long long k2 =
                partial[((size_t)q * T_STEPS + t) * BCAP + bi];
            if (k2 > best) best = k2;
        }
        vArr[tid] = 1023 - (int)((best >> 16) & 0xffffull);
        bArr[tid] = (int)(best & 0xffffull);
    }
    __syncthreads();

    const int l32 = tid & 31;
    for (int q = tid >> 5; q < nb; q += 8) {
        const int b = bArr[q], v = vArr[q];
        ((float4*)out)[b * 32 + l32] =
            ((const float4*)L)[(size_t)(t * V_VECS + v) * 32 + l32];
    }
}

extern "C" void kernel_launch(void* const* d_in, const int* in_sizes, int n_in,
                              void* d_out, int out_size, void* d_ws, size_t ws_size,
                              hipStream_t stream) {
    const float* X  = (const float*)d_in[0];   // (B, D, 1) f32
    const float* L  = (const float*)d_in[1];   // (T, V, D) f32
    const int* idx  = (const int*)d_in[2];     // (B,) int
    float* out      = (float*)d_out;           // (B, D) f32

    char* ws = (char*)d_ws;
    int* counts               = (int*)ws;                              // 64 B
    unsigned long long* part  = (unsigned long long*)(ws + 4096);      // 4 MiB

    hipLaunchKernelGGL(k_score,  dim3(16, 16, 2), dim3(64),  0, stream,
                       X, L, idx, part, counts);
    hipLaunchKernelGGL(k_gather, dim3(32, 16),    dim3(256), 0, stream,
                       L, counts, part, out);
}

// Round 9
// 36.341 us; speedup vs baseline: 1.3856x; 1.3856x over previous
//
#include <hip/hip_runtime.h>
#include <cstdint>

#define T_STEPS 16
#define V_VECS  1024
#define D_DIM   128
#define B_BATCH 2048
#define BCAP    2048          // per-t list capacity (bulletproof: n <= B)

// ---------------------------------------------------------------------------
// k_score: grid (16 vtiles, 16 t, 2 z), block = 128 threads (2 waves).
// Tile 64v x 64b; thread tile 8v x 4b (grid 8 tv x 16 tb):
//   per k: 2 ds_read_b128 (A, 2-way bank alias = free) + 1 ds_read_b128
//   (X, 8-way same-address broadcast = free) + 32 FMA  => 1.5 B/FMA.
// LDS 69 KB -> 2 blocks/CU = 4 waves/CU, 512 blocks (2/CU), two INDEPENDENT
// blocks per CU overlap staging with compute (round-8 lesson: never 1 wave).
//
// Phase 0: ballot+prefix bucketing (16 rounds, 2 waves coordinated via LDS).
//          Deterministic => all blocks of t derive the IDENTICAL blist.
// Phase 1: stage A^T k-major (half-row per thread) + fused inverse norms
//          (pairwise shfl_xor(1) combine).
// Phase 2: chunk loop (cs = z*64; cs += 128): stage X^T, 8x4 register GEMM,
//          invnorm scale, argmax over 8 local v, shfl_xor {1,2,4} across tv
//          lanes (tie -> lowest v, matches jnp.argmax), plain store of packed
//          (ordered_score:32 | (1023-v):16 | b:16) to partial[vt][t][bi].
//          Cross-block visibility via the KERNEL BOUNDARY only (intra-kernel
//          protocols failed rounds 4-6).
// ---------------------------------------------------------------------------
__global__ __launch_bounds__(128) void k_score(const float* __restrict__ X,
                                               const float* __restrict__ L,
                                               const int* __restrict__ idx,
                                               unsigned long long* __restrict__ partial,
                                               int* __restrict__ counts) {
    __shared__ __align__(16) float As[D_DIM][64];   // 32 KB
    __shared__ __align__(16) float Xs[D_DIM][64];   // 32 KB
    __shared__ float invn_s[64];
    __shared__ unsigned short blist[BCAP];          // 4 KB
    __shared__ int wcnt[2];

    const int t    = blockIdx.y;
    const int vt   = blockIdx.x;
    const int v0   = vt * 64;
    const int z    = blockIdx.z;
    const int tid  = threadIdx.x;                   // 0..127
    const int lane = tid & 63;
    const int w    = tid >> 6;

    // ---- phase 0: bucketing (identical blist in every block of t) ----
    int n = 0;
    for (int r = 0; r < 16; ++r) {
        const int b = r * 128 + tid;
        const bool m = (idx[b] == t);
        const unsigned long long bal = __ballot(m);
        const int wpre = __popcll(bal & ((1ull << lane) - 1ull));
        if (lane == 0) wcnt[w] = __popcll(bal);
        __syncthreads();
        const int c0 = wcnt[0], c1 = wcnt[1];
        if (m) blist[n + (w ? c0 : 0) + wpre] = (unsigned short)b;
        n += c0 + c1;
        __syncthreads();
    }
    if (vt == 0 && z == 0 && tid == 0) counts[t] = n;   // before early return
    if (z * 64 >= n) return;             // uniform across blocks of t

    // ---- phase 1: stage A^T (k-major, half-row per thread) + norms ----
    const int vrow = tid >> 1;           // 0..63
    const int half = tid & 1;
    const float4* LA = (const float4*)(L + (size_t)(t * V_VECS + v0) * D_DIM);
    float ss = 0.f;
    #pragma unroll 4
    for (int p = 0; p < 16; ++p) {
        const int k4 = half * 16 + p;    // 0..31
        const float4 g = LA[vrow * 32 + k4];
        As[4 * k4 + 0][vrow] = g.x;
        As[4 * k4 + 1][vrow] = g.y;
        As[4 * k4 + 2][vrow] = g.z;
        As[4 * k4 + 3][vrow] = g.w;
        ss += g.x * g.x + g.y * g.y + g.z * g.z + g.w * g.w;
    }
    ss += __shfl_xor(ss, 1);             // combine the two half-rows
    if (half == 0) invn_s[vrow] = rsqrtf(fmaxf(ss, 1e-12f));
    // invn_s visible after the barrier inside the chunk loop.

    const int tv = tid & 7;              // v-octet: v = v0 + tv*8 + i
    const int tb = tid >> 3;             // b-quad:  b-slot = cs + tb*4 + j
    const float4* XA = (const float4*)X;

    // ---- phase 2: chunk loop ----
    for (int cs = z * 64; cs < n; cs += 128) {
        __syncthreads();                 // prior Xs reads + invn writes settled

        const int bl = cs + vrow;
        const int bg = (bl < n) ? (int)blist[bl] : -1;
        const float4* xr = XA + (size_t)(bg < 0 ? 0 : bg) * 32;
        #pragma unroll 4
        for (int p = 0; p < 16; ++p) {
            const int k4 = half * 16 + p;
            float4 g = make_float4(0.f, 0.f, 0.f, 0.f);
            if (bg >= 0) g = xr[k4];
            Xs[4 * k4 + 0][vrow] = g.x;
            Xs[4 * k4 + 1][vrow] = g.y;
            Xs[4 * k4 + 2][vrow] = g.z;
            Xs[4 * k4 + 3][vrow] = g.w;
        }
        __syncthreads();

        float acc[8][4] = {};
        #pragma unroll 4
        for (int k = 0; k < D_DIM; ++k) {
            const float4 a0 = *(const float4*)&As[k][tv * 8];
            const float4 a1 = *(const float4*)&As[k][tv * 8 + 4];
            const float4 x0 = *(const float4*)&Xs[k][tb * 4];
            const float a[8] = {a0.x, a0.y, a0.z, a0.w, a1.x, a1.y, a1.z, a1.w};
            const float x[4] = {x0.x, x0.y, x0.z, x0.w};
            #pragma unroll
            for (int i = 0; i < 8; ++i)
                #pragma unroll
                for (int j = 0; j < 4; ++j)
                    acc[i][j] += a[i] * x[j];
        }

        // ---- epilogue: argmax over v per b ----
        const float4 n0 = *(const float4*)&invn_s[tv * 8];
        const float4 n1 = *(const float4*)&invn_s[tv * 8 + 4];
        const float inv[8] = {n0.x, n0.y, n0.z, n0.w, n1.x, n1.y, n1.z, n1.w};

        #pragma unroll
        for (int j = 0; j < 4; ++j) {
            float s = acc[0][j] * inv[0];
            int   c = v0 + tv * 8;
            #pragma unroll
            for (int i = 1; i < 8; ++i) {
                const float si = acc[i][j] * inv[i];
                const int   ci = v0 + tv * 8 + i;
                if (si > s) { s = si; c = ci; }      // strict: lowest v wins tie
            }
            #pragma unroll
            for (int m = 1; m <= 4; m <<= 1) {       // reduce across tv lanes
                const float u  = __shfl_xor(s, m);
                const int   cu = __shfl_xor(c, m);
                if (u > s || (u == s && cu < c)) { s = u; c = cu; }
            }
            if (tv == 0) {
                const int bi = cs + tb * 4 + j;
                if (bi < n) {
                    unsigned int ub = __float_as_uint(s);
                    ub = (ub & 0x80000000u) ? ~ub : (ub | 0x80000000u);
                    const unsigned long long key =
                        ((unsigned long long)ub << 32) |
                        ((unsigned long long)(unsigned)(1023 - c) << 16) |
                        (unsigned long long)blist[bi];
                    partial[((size_t)vt * T_STEPS + t) * BCAP + bi] = key;
                }
            }
        }
    }
}

// ---------------------------------------------------------------------------
// k_gather: grid (32 bi-chunks, 16 t), block 256. Reads counts/partial across
// the kernel boundary (full visibility). Per valid bi: max-reduce the 16
// vt-keys (higher score wins; tie -> higher (1023-v) -> lower v, matching
// jnp.argmax), decode (b, v), copy the raw winning vector (bit-exact).
// ---------------------------------------------------------------------------
__global__ __launch_bounds__(256) void k_gather(const float* __restrict__ L,
                                                const int* __restrict__ counts,
                                                const unsigned long long* __restrict__ partial,
                                                float* __restrict__ out) {
    __shared__ int vArr[64];
    __shared__ int bArr[64];

    const int t  = blockIdx.y;
    const int cs = blockIdx.x * 64;
    const int n  = counts[t];
    if (cs >= n) return;

    const int tid = threadIdx.x;
    const int nb  = min(64, n - cs);
    if (tid < nb) {
        const int bi = cs + tid;
        unsigned long long best = partial[(size_t)t * BCAP + bi];   // vt=0
        #pragma unroll
        for (int q = 1; q < 16; ++q) {
            const unsigned long long k2 =
                partial[((size_t)q * T_STEPS + t) * BCAP + bi];
            if (k2 > best) best = k2;
        }
        vArr[tid] = 1023 - (int)((best >> 16) & 0xffffull);
        bArr[tid] = (int)(best & 0xffffull);
    }
    __syncthreads();

    const int l32 = tid & 31;
    for (int q = tid >> 5; q < nb; q += 8) {
        const int b = bArr[q], v = vArr[q];
        ((float4*)out)[b * 32 + l32] =
            ((const float4*)L)[(size_t)(t * V_VECS + v) * 32 + l32];
    }
}

extern "C" void kernel_launch(void* const* d_in, const int* in_sizes, int n_in,
                              void* d_out, int out_size, void* d_ws, size_t ws_size,
                              hipStream_t stream) {
    const float* X  = (const float*)d_in[0];   // (B, D, 1) f32
    const float* L  = (const float*)d_in[1];   // (T, V, D) f32
    const int* idx  = (const int*)d_in[2];     // (B,) int
    float* out      = (float*)d_out;           // (B, D) f32

    char* ws = (char*)d_ws;
    int* counts               = (int*)ws;                              // 64 B
    unsigned long long* part  = (unsigned long long*)(ws + 4096);      // 4 MiB

    hipLaunchKernelGGL(k_score,  dim3(16, 16, 2), dim3(128), 0, stream,
                       X, L, idx, part, counts);
    hipLaunchKernelGGL(k_gather, dim3(32, 16),    dim3(256), 0, stream,
                       L, counts, part, out);
}

// Round 10
// 30.614 us; speedup vs baseline: 1.6447x; 1.1870x over previous
//
#include <hip/hip_runtime.h>
#include <cstdint>

#define T_STEPS 16
#define V_VECS  1024
#define D_DIM   128
#define B_BATCH 2048
#define BCAP    2048          // per-t list capacity (bulletproof: n <= B)

// ---------------------------------------------------------------------------
// k_score: grid (16 vtiles, 16 t, 4 z), block 256 = 16(tv) x 16(tb).
// Tile 64v x 64b, 4x4 thread tile. LDS holds ONLY the A-tile (k-major) +
// u16 blist => ~38 KB -> 4 blocks/CU = 16 waves/CU (r7-r9 fit: T = 20 +
// 64/waves, so 16 waves cuts the latency term to ~4us). X is read directly
// from global per k4-group: 4 unique 16B addresses per wave-instr (16-way
// broadcast, L1-resident 32KB working set) - removes 32KB Xs, its staging
// pass and barrier, and halves LDS traffic to 1 B/FMA (A-side only).
//
// Phase 0: all 8 ballot rounds issued with NO intervening barriers (loads
//          pipeline), one barrier, uniform prefix from wcnt[8][4], scatter.
//          Deterministic => all blocks of t derive the IDENTICAL blist.
// Phase 1: stage A^T k-major + fused inverse norms (npart reduce).
// Phase 2: chunk loop (cs = z*64; cs += 256): 4x4 register GEMM with X from
//          global; identical per-k FMA order to round 7 => bit-identical
//          scores. Epilogue: invnorm scale, argmax over 4 local v, shfl_xor
//          {1,2,4,8} across tv lanes (tie -> lowest v, matches jnp.argmax),
//          plain store of packed (ordered_score:32 | (1023-v):16 | b:16) to
//          partial[vt][t][bi]. Cross-block visibility via the KERNEL
//          BOUNDARY only (intra-kernel protocols failed rounds 4-6).
// ---------------------------------------------------------------------------
__global__ __launch_bounds__(256, 4) void k_score(const float* __restrict__ X,
                                                  const float* __restrict__ L,
                                                  const int* __restrict__ idx,
                                                  unsigned long long* __restrict__ partial,
                                                  int* __restrict__ counts) {
    __shared__ __align__(16) float As[D_DIM][64];   // 32 KB
    __shared__ float npart[4][64];                  // 1 KB
    __shared__ float invn_s[64];
    __shared__ unsigned short blist[BCAP];          // 4 KB
    __shared__ int wcnt[8][4];

    const int t    = blockIdx.y;
    const int vt   = blockIdx.x;
    const int v0   = vt * 64;
    const int z    = blockIdx.z;
    const int tid  = threadIdx.x;
    const int lane = tid & 63;
    const int w    = tid >> 6;

    // ---- phase 0: barrier-light bucketing ----
    bool mm[8]; int wpre[8];
    #pragma unroll
    for (int r = 0; r < 8; ++r) {
        const bool m = (idx[r * 256 + tid] == t);
        const unsigned long long bal = __ballot(m);
        mm[r]   = m;
        wpre[r] = __popcll(bal & ((1ull << lane) - 1ull));
        if (lane == 0) wcnt[r][w] = __popcll(bal);
    }
    __syncthreads();
    int run = 0;
    #pragma unroll
    for (int r = 0; r < 8; ++r) {
        int base = run;
        #pragma unroll
        for (int w2 = 0; w2 < 4; ++w2) {
            const int c = wcnt[r][w2];      // LDS broadcast (uniform)
            if (w2 < w) base += c;
            run += c;
        }
        if (mm[r]) blist[base + wpre[r]] = (unsigned short)(r * 256 + tid);
    }
    const int n = run;
    if (vt == 0 && z == 0 && tid == 0) counts[t] = n;   // before early return
    if (z * 64 >= n) return;             // uniform across blocks of t

    // ---- phase 1: stage A^T (k-major) + fused inverse norms ----
    const float4* LA = (const float4*)(L + (size_t)(t * V_VECS + v0) * D_DIM);
    float ss = 0.f;
    #pragma unroll
    for (int p = 0; p < 8; ++p) {
        const int k4 = w + 4 * p;              // 0..31
        const float4 g = LA[lane * 32 + k4];
        As[4 * k4 + 0][lane] = g.x;
        As[4 * k4 + 1][lane] = g.y;
        As[4 * k4 + 2][lane] = g.z;
        As[4 * k4 + 3][lane] = g.w;
        ss += g.x * g.x + g.y * g.y + g.z * g.z + g.w * g.w;
    }
    npart[w][lane] = ss;
    __syncthreads();
    if (tid < 64) {
        const float s = npart[0][tid] + npart[1][tid] + npart[2][tid] + npart[3][tid];
        invn_s[tid] = rsqrtf(fmaxf(s, 1e-12f));
    }
    // invn_s + blist visible after the barrier inside the chunk loop.

    const int tv = tid & 15;     // v-group: v = v0 + tv*4 + i
    const int tb = tid >> 4;     // b-group: b-slot = cs + tb*4 + j
    const float4* XA = (const float4*)X;

    // ---- phase 2: chunk loop (X direct from global/L1) ----
    for (int cs = z * 64; cs < n; cs += 256) {
        __syncthreads();                 // invn_s/blist visible (iter 1)

        const int bsl = cs + tb * 4;
        const float4* xp0 = XA + (size_t)((bsl + 0 < n) ? blist[bsl + 0] : 0) * 32;
        const float4* xp1 = XA + (size_t)((bsl + 1 < n) ? blist[bsl + 1] : 0) * 32;
        const float4* xp2 = XA + (size_t)((bsl + 2 < n) ? blist[bsl + 2] : 0) * 32;
        const float4* xp3 = XA + (size_t)((bsl + 3 < n) ? blist[bsl + 3] : 0) * 32;

        float acc[4][4] = {};
        #pragma unroll 4
        for (int k4 = 0; k4 < 32; ++k4) {
            const float4 q0 = xp0[k4];
            const float4 q1 = xp1[k4];
            const float4 q2 = xp2[k4];
            const float4 q3 = xp3[k4];
            const float xk[4][4] = {{q0.x, q1.x, q2.x, q3.x},
                                    {q0.y, q1.y, q2.y, q3.y},
                                    {q0.z, q1.z, q2.z, q3.z},
                                    {q0.w, q1.w, q2.w, q3.w}};
            #pragma unroll
            for (int c = 0; c < 4; ++c) {
                const float4 av = *(const float4*)&As[4 * k4 + c][tv * 4];
                const float a[4] = {av.x, av.y, av.z, av.w};
                #pragma unroll
                for (int i = 0; i < 4; ++i)
                    #pragma unroll
                    for (int j = 0; j < 4; ++j)
                        acc[i][j] += a[i] * xk[c][j];
            }
        }

        // ---- epilogue: argmax over v per b ----
        const float4 inv4 = *(const float4*)&invn_s[tv * 4];
        const float invp[4] = {inv4.x, inv4.y, inv4.z, inv4.w};

        #pragma unroll
        for (int j = 0; j < 4; ++j) {
            float s = acc[0][j] * invp[0];
            int   c = v0 + tv * 4;
            #pragma unroll
            for (int i = 1; i < 4; ++i) {
                const float si = acc[i][j] * invp[i];
                const int   ci = v0 + tv * 4 + i;
                if (si > s) { s = si; c = ci; }      // strict: lowest v wins tie
            }
            #pragma unroll
            for (int m = 8; m >= 1; m >>= 1) {       // reduce across tv lanes
                const float u  = __shfl_xor(s, m);
                const int   cu = __shfl_xor(c, m);
                if (u > s || (u == s && cu < c)) { s = u; c = cu; }
            }
            if (tv == 0) {
                const int bi = cs + tb * 4 + j;
                if (bi < n) {
                    unsigned int ub = __float_as_uint(s);
                    ub = (ub & 0x80000000u) ? ~ub : (ub | 0x80000000u);
                    const unsigned long long key =
                        ((unsigned long long)ub << 32) |
                        ((unsigned long long)(unsigned)(1023 - c) << 16) |
                        (unsigned long long)blist[bi];
                    partial[((size_t)vt * T_STEPS + t) * BCAP + bi] = key;
                }
            }
        }
    }
}

// ---------------------------------------------------------------------------
// k_gather: grid (32 bi-chunks, 16 t), block 256. Reads counts/partial across
// the kernel boundary (full visibility). Per valid bi: max-reduce the 16
// vt-keys (higher score wins; tie -> higher (1023-v) -> lower v, matching
// jnp.argmax), decode (b, v), copy the raw winning vector (bit-exact).
// ---------------------------------------------------------------------------
__global__ __launch_bounds__(256) void k_gather(const float* __restrict__ L,
                                                const int* __restrict__ counts,
                                                const unsigned long long* __restrict__ partial,
                                                float* __restrict__ out) {
    __shared__ int vArr[64];
    __shared__ int bArr[64];

    const int t  = blockIdx.y;
    const int cs = blockIdx.x * 64;
    const int n  = counts[t];
    if (cs >= n) return;

    const int tid = threadIdx.x;
    const int nb  = min(64, n - cs);
    if (tid < nb) {
        const int bi = cs + tid;
        unsigned long long best = partial[(size_t)t * BCAP + bi];   // vt=0
        #pragma unroll
        for (int q = 1; q < 16; ++q) {
            const unsigned long long k2 =
                partial[((size_t)q * T_STEPS + t) * BCAP + bi];
            if (k2 > best) best = k2;
        }
        vArr[tid] = 1023 - (int)((best >> 16) & 0xffffull);
        bArr[tid] = (int)(best & 0xffffull);
    }
    __syncthreads();

    const int l32 = tid & 31;
    for (int q = tid >> 5; q < nb; q += 8) {
        const int b = bArr[q], v = vArr[q];
        ((float4*)out)[b * 32 + l32] =
            ((const float4*)L)[(size_t)(t * V_VECS + v) * 32 + l32];
    }
}

extern "C" void kernel_launch(void* const* d_in, const int* in_sizes, int n_in,
                              void* d_out, int out_size, void* d_ws, size_t ws_size,
                              hipStream_t stream) {
    const float* X  = (const float*)d_in[0];   // (B, D, 1) f32
    const float* L  = (const float*)d_in[1];   // (T, V, D) f32
    const int* idx  = (const int*)d_in[2];     // (B,) int
    float* out      = (float*)d_out;           // (B, D) f32

    char* ws = (char*)d_ws;
    int* counts               = (int*)ws;                              // 64 B
    unsigned long long* part  = (unsigned long long*)(ws + 4096);      // 4 MiB

    hipLaunchKernelGGL(k_score,  dim3(16, 16, 4), dim3(256), 0, stream,
                       X, L, idx, part, counts);
    hipLaunchKernelGGL(k_gather, dim3(32, 16),    dim3(256), 0, stream,
                       L, counts, part, out);
}